// Round 17
// baseline (889.201 us; speedup 1.0000x reference)
//
#include <hip/hip_runtime.h>

#define BATCH 64
#define SEQT  2048
#define DIM   256   // INPUT_SIZE
#define HID   256   // HIDDEN_SIZE
#define NSEG  16
#define SEGT  128   // timesteps per xproj segment block

typedef _Float16 half_t;
typedef _Float16 half2_t __attribute__((ext_vector_type(2)));
typedef _Float16 half4_t __attribute__((ext_vector_type(4)));
typedef _Float16 half8_t __attribute__((ext_vector_type(8)));
typedef float    float4_t __attribute__((ext_vector_type(4)));

__device__ __forceinline__ half8_t cvt8(float4_t a, float4_t b) {
  half8_t r;
  r[0] = (half_t)a[0]; r[1] = (half_t)a[1]; r[2] = (half_t)a[2]; r[3] = (half_t)a[3];
  r[4] = (half_t)b[0]; r[5] = (half_t)b[1]; r[6] = (half_t)b[2]; r[7] = (half_t)b[3];
  return r;
}
// extract half2 #c from a half8 (c MUST be a parse-time literal)
#define H2X(v, c) __builtin_shufflevector((v), (v), 2*(c), 2*(c)+1)

// DPP lane-move (pure VALU).  0xB1 = quad_perm lane^1; 0x4E = quad_perm
// lane^2; 0x141 = row_half_mirror (XOR7 within 8).
template<int CTRL>
__device__ __forceinline__ float dpp_mov(float a) {
  int t = __builtin_amdgcn_mov_dpp(__builtin_bit_cast(int, a), CTRL, 0xF, 0xF, true);
  return __builtin_bit_cast(float, t);
}

#define RNN_BAR() asm volatile("s_waitcnt lgkmcnt(0)\n\ts_barrier" ::: "memory")

// Force VGPR allocation >= 168 so only ONE 512-thread block fits a CU
// (3 waves/SIMD max): rnn blocks get exclusive CUs, producers can't
// co-schedule beside them and steal LDS/cache/issue resources.
#define FORCE_EXCLUSIVE_CU()                                                   \
  asm volatile("" :::                                                          \
    "v128","v129","v130","v131","v132","v133","v134","v135",                   \
    "v136","v137","v138","v139","v140","v141","v142","v143",                   \
    "v144","v145","v146","v147","v148","v149","v150","v151",                   \
    "v152","v153","v154","v155","v156","v157","v158","v159",                   \
    "v160","v161","v162","v163","v164","v165","v166","v167")

// producer->consumer flag poll: lane 0 acquires (agent scope -> L1/L2 inv),
// block barrier propagates visibility to all waves of the block.
__device__ __forceinline__ void poll_flag(const unsigned int* f) {
  if (threadIdx.x == 0) {
    while (__hip_atomic_load(f, __ATOMIC_ACQUIRE, __HIP_MEMORY_SCOPE_AGENT) == 0u)
      __builtin_amdgcn_s_sleep(2);
  }
  __syncthreads();
}

// ---------------------------------------------------------------------------
// prep: W_xh fp32 -> f16 into d_ws[0..128KB); block 0 also zeros the 1024
// chain x segment flags at d_ws[128KB..+4KB).
// ---------------------------------------------------------------------------
__global__ __launch_bounds__(256) void prep_kernel(
    const float* __restrict__ W, half_t* __restrict__ Wh,
    unsigned int* __restrict__ flags)
{
  const int i = (blockIdx.x * 256 + threadIdx.x) * 4;
  float4_t v = *(const float4_t*)(W + i);
  half4_t o; o[0]=(half_t)v[0]; o[1]=(half_t)v[1]; o[2]=(half_t)v[2]; o[3]=(half_t)v[3];
  *(half4_t*)(Wh + i) = o;
  if (blockIdx.x == 0) {
    flags[threadIdx.x]       = 0u;
    flags[threadIdx.x + 256] = 0u;
    flags[threadIdx.x + 512] = 0u;
    flags[threadIdx.x + 768] = 0u;
  }
}

// ---------------------------------------------------------------------------
// v6 rnn step (byte-equivalent math to the verified 851us kernel)
// ---------------------------------------------------------------------------
#define RNN_STEP(U, XQ)                                                        \
  {                                                                            \
    const int t = t4 + (U);                                                    \
    const int tp = (t + 4 < T) ? (t + 4) : (T - 1);                            \
    float xnew = outp[(long)tp * HID];                                         \
    half8_t hv[4];                                                             \
    _Pragma("unroll")                                                          \
    for (int s = 0; s < 4; ++s)                                                \
      hv[s] = *(const half8_t*)(hraw[(U) & 1] + rb + 16 * s);                  \
    float a0 = 0.f, a1 = 0.f, a2 = 0.f, a3 = 0.f;                              \
    _Pragma("unroll")                                                          \
    for (int s = 0; s < 4; ++s) {                                              \
      a0 = __builtin_amdgcn_fdot2(H2X(w8[0][s], 0), H2X(hv[s], 0), a0, false); \
      a0 = __builtin_amdgcn_fdot2(H2X(w8[0][s], 1), H2X(hv[s], 1), a0, false); \
      a0 = __builtin_amdgcn_fdot2(H2X(w8[0][s], 2), H2X(hv[s], 2), a0, false); \
      a0 = __builtin_amdgcn_fdot2(H2X(w8[0][s], 3), H2X(hv[s], 3), a0, false); \
      a1 = __builtin_amdgcn_fdot2(H2X(w8[1][s], 0), H2X(hv[s], 0), a1, false); \
      a1 = __builtin_amdgcn_fdot2(H2X(w8[1][s], 1), H2X(hv[s], 1), a1, false); \
      a1 = __builtin_amdgcn_fdot2(H2X(w8[1][s], 2), H2X(hv[s], 2), a1, false); \
      a1 = __builtin_amdgcn_fdot2(H2X(w8[1][s], 3), H2X(hv[s], 3), a1, false); \
      a2 = __builtin_amdgcn_fdot2(H2X(w8[2][s], 0), H2X(hv[s], 0), a2, false); \
      a2 = __builtin_amdgcn_fdot2(H2X(w8[2][s], 1), H2X(hv[s], 1), a2, false); \
      a2 = __builtin_amdgcn_fdot2(H2X(w8[2][s], 2), H2X(hv[s], 2), a2, false); \
      a2 = __builtin_amdgcn_fdot2(H2X(w8[2][s], 3), H2X(hv[s], 3), a2, false); \
      a3 = __builtin_amdgcn_fdot2(H2X(w8[3][s], 0), H2X(hv[s], 0), a3, false); \
      a3 = __builtin_amdgcn_fdot2(H2X(w8[3][s], 1), H2X(hv[s], 1), a3, false); \
      a3 = __builtin_amdgcn_fdot2(H2X(w8[3][s], 2), H2X(hv[s], 2), a3, false); \
      a3 = __builtin_amdgcn_fdot2(H2X(w8[3][s], 3), H2X(hv[s], 3), a3, false); \
    }                                                                          \
    float r0 = kA ? a0 : a2;                                                   \
    float r1 = kA ? a1 : a3;                                                   \
    float b0 = (kA ? a2 : a0) + dpp_mov<0x141>(r0);                            \
    float b1 = (kA ? a3 : a1) + dpp_mov<0x141>(r1);                            \
    float rB = kB ? b0 : b1;                                                   \
    float c  = (kB ? b1 : b0) + dpp_mov<0x4E>(rB);                             \
    float fin = c + dpp_mov<0xB1>(c);                                          \
    float y = fmaxf(fin + (XQ), 0.f);                                          \
    outp[(long)t * HID] = y;                                                   \
    *(half_t*)(hraw[((U) & 1) ^ 1] + hwb) = (half_t)y;                         \
    XQ = xnew;                                                                 \
    RNN_BAR();                                                                 \
  }

// ---------------------------------------------------------------------------
// FUSED kernel, grid 1088 x 512:
//   blocks 0..63    : rnn chain (v6 structure) gated by per-segment flags
//   blocks 64..1087 : xproj tile (seg k = (b-64)>>6, chain c = (b-64)&63),
//                     segment-major so every chain's seg 0 lands first.
// VGPR forced >= 168 -> ONE block per CU: no producer ever co-resides with
// an rnn block (round-16 counters showed co-residency cost ~45us that
// setprio could not remove).
// ---------------------------------------------------------------------------
__global__ __launch_bounds__(512, 1) void fused_kernel(
    const float* __restrict__ x, const half_t* __restrict__ Wxh16,
    const float* __restrict__ Whh, const float* __restrict__ bh,
    float* __restrict__ out, unsigned int* __restrict__ flags, int T)
{
  FORCE_EXCLUSIVE_CU();

  if (blockIdx.x >= 64) {
    // ================= xproj producer =================
    const int b = blockIdx.x - 64;
    const int k = b >> 6;        // segment
    const int c = b & 63;        // chain
    const int lane = threadIdx.x & 63;
    const int w = threadIdx.x >> 6;    // 0..7, owns n-tiles 2w, 2w+1
    const int r16 = lane & 15;
    const int kg = lane >> 4;
    const long m0 = ((long)c * NSEG + k) * SEGT;   // global row base

    half8_t bfr[2][8];
    float bb[2];
    #pragma unroll
    for (int i = 0; i < 2; ++i) {
      const int nt = w * 2 + i;
      const half_t* wr = Wxh16 + (nt * 16 + r16) * (long)DIM + kg * 8;
      #pragma unroll
      for (int kf = 0; kf < 8; ++kf)
        bfr[i][kf] = *(const half8_t*)(wr + kf * 32);
      bb[i] = bh[nt * 16 + r16];
    }
    #pragma unroll 1
    for (int mi = 0; mi < 8; ++mi) {
      const long mrow = m0 + mi * 16;
      half8_t a[8];
      const float* xr = x + (mrow + r16) * (long)DIM + kg * 8;
      #pragma unroll
      for (int kf = 0; kf < 8; ++kf) {
        float4_t x0 = *(const float4_t*)(xr + kf * 32);
        float4_t x1 = *(const float4_t*)(xr + kf * 32 + 4);
        a[kf] = cvt8(x0, x1);
      }
      #pragma unroll
      for (int i = 0; i < 2; ++i) {
        float4_t acc = {bb[i], bb[i], bb[i], bb[i]};
        #pragma unroll
        for (int kf = 0; kf < 8; ++kf)
          acc = __builtin_amdgcn_mfma_f32_16x16x32_f16(a[kf], bfr[i][kf], acc, 0, 0, 0);
        float* op = out + (mrow + kg * 4) * (long)HID + (w * 2 + i) * 16 + r16;
        #pragma unroll
        for (int r = 0; r < 4; ++r) op[(long)r * HID] = acc[r];
      }
    }
    __syncthreads();   // drains vmcnt(0): all block stores complete
    if (threadIdx.x == 0)
      __hip_atomic_store(flags + ((c << 4) | k), 1u, __ATOMIC_RELEASE,
                         __HIP_MEMORY_SCOPE_AGENT);
    return;
  }

  // ================= rnn consumer (v6 @851us) =================
  __shared__ alignas(128) unsigned char hraw[2][8 * 80];

  const int chain = blockIdx.x;
  const int tid = threadIdx.x;
  const int l   = tid & 63;
  const int w   = tid >> 6;                // wave 0..7
  const int g   = l & 7;                   // K-chunk: columns [32g, 32g+32)
  const int j0  = w * 32 + (l >> 3) * 4;   // partial rows [j0, j0+4)
  const int rb  = g * 80;                  // LDS read base (bytes)
  const int jown = j0 + ((l >> 1) & 3);    // output row OWNED post-reduce
  const int hwb = ((jown >> 5) * 80 + (jown & 31) * 2);  // LDS write byte
  const bool kA = (l & 4) != 0;
  const bool kB = (l & 2) != 0;
  const unsigned int* fl = flags + (chain << 4);
  float* outp = out + (long)chain * SEQT * HID + jown;

  // W_hh[j0+i][32g + 8s .. +8] -> w8[i][s]  (64 VGPRs, static indexing)
  half8_t w8[4][4];
  #pragma unroll
  for (int i = 0; i < 4; ++i) {
    const float* wr = Whh + (long)(j0 + i) * HID + g * 32;
    #pragma unroll
    for (int s = 0; s < 4; ++s) {
      float4_t v0 = *(const float4_t*)(wr + s * 8);
      float4_t v1 = *(const float4_t*)(wr + s * 8 + 4);
      w8[i][s] = cvt8(v0, v1);
    }
  }

  // h_0 = 0 (covers data+pads of buffer 0)
  if (tid < 160) ((float*)hraw[0])[tid] = 0.f;

  // wait for segment 0, then 4-deep xp prefetch (t = 0..3, all in seg 0)
  poll_flag(fl + 0);
  float xq0 = outp[0L * HID];
  float xq1 = outp[1L * HID];
  float xq2 = outp[2L * HID];
  float xq3 = outp[3L * HID];
  RNN_BAR();

  #pragma unroll 1
  for (int seg = 0; seg < NSEG; ++seg) {
    // loads issued during seg touch up to t = 128*seg+127+4 -> seg+1
    const int ps = (seg + 1 < NSEG) ? (seg + 1) : (NSEG - 1);
    poll_flag(fl + ps);
    const int tend = seg * SEGT + SEGT;
    #pragma unroll 1
    for (int t4 = seg * SEGT; t4 < tend; t4 += 4) {
      RNN_STEP(0, xq0)
      RNN_STEP(1, xq1)
      RNN_STEP(2, xq2)
      RNN_STEP(3, xq3)
    }
  }
}

// ===========================================================================
// FALLBACK (ws too small for Wh+flags): round-13 path, proven @940us
// ===========================================================================
__global__ __launch_bounds__(256) void xproj_kernel(
    const float* __restrict__ x, const float* __restrict__ Wxh,
    const float* __restrict__ bh, float* __restrict__ out)
{
  const int lane = threadIdx.x & 63;
  const int wave = threadIdx.x >> 6;
  const int r16  = lane & 15;
  const int kg   = lane >> 4;
  const long m0  = (long)blockIdx.x * 64 + wave * 16;

  half8_t a[8];
  const float* xr = x + (m0 + r16) * (long)DIM + kg * 8;
  #pragma unroll
  for (int kf = 0; kf < 8; ++kf) {
    float4_t x0 = *(const float4_t*)(xr + kf * 32);
    float4_t x1 = *(const float4_t*)(xr + kf * 32 + 4);
    a[kf] = cvt8(x0, x1);
  }
  for (int nt = 0; nt < 16; ++nt) {
    const float* wr = Wxh + (nt * 16 + r16) * (long)DIM + kg * 8;
    float bb = bh[nt * 16 + r16];
    float4_t acc = {bb, bb, bb, bb};
    #pragma unroll
    for (int kf = 0; kf < 8; ++kf) {
      float4_t w0 = *(const float4_t*)(wr + kf * 32);
      float4_t w1 = *(const float4_t*)(wr + kf * 32 + 4);
      acc = __builtin_amdgcn_mfma_f32_16x16x32_f16(a[kf], cvt8(w0, w1), acc, 0, 0, 0);
    }
    float* op = out + (m0 + kg * 4) * (long)HID + nt * 16 + r16;
    #pragma unroll
    for (int r = 0; r < 4; ++r) op[(long)r * HID] = acc[r];
  }
}

__global__ __launch_bounds__(512, 1) void rnn_kernel(
    const float* __restrict__ Whh, float* __restrict__ out, int T)
{
  __shared__ alignas(128) unsigned char hraw[2][8 * 80];

  const int tid = threadIdx.x;
  const int l   = tid & 63;
  const int w   = tid >> 6;
  const int g   = l & 7;
  const int j0  = w * 32 + (l >> 3) * 4;
  const int rb  = g * 80;
  const int jown = j0 + ((l >> 1) & 3);
  const int hwb = ((jown >> 5) * 80 + (jown & 31) * 2);
  const bool kA = (l & 4) != 0;
  const bool kB = (l & 2) != 0;
  float* outp = out + (long)blockIdx.x * SEQT * HID + jown;

  half8_t w8[4][4];
  #pragma unroll
  for (int i = 0; i < 4; ++i) {
    const float* wr = Whh + (long)(j0 + i) * HID + g * 32;
    #pragma unroll
    for (int s = 0; s < 4; ++s) {
      float4_t v0 = *(const float4_t*)(wr + s * 8);
      float4_t v1 = *(const float4_t*)(wr + s * 8 + 4);
      w8[i][s] = cvt8(v0, v1);
    }
  }
  if (tid < 160) ((float*)hraw[0])[tid] = 0.f;

  float xq0 = outp[0L * HID];
  float xq1 = outp[1L * HID];
  float xq2 = outp[2L * HID];
  float xq3 = outp[3L * HID];
  RNN_BAR();

  #pragma unroll 1
  for (int t4 = 0; t4 < T; t4 += 4) {
    RNN_STEP(0, xq0)
    RNN_STEP(1, xq1)
    RNN_STEP(2, xq2)
    RNN_STEP(3, xq3)
  }
}

// ===========================================================================
extern "C" void kernel_launch(void* const* d_in, const int* in_sizes, int n_in,
                              void* d_out, int out_size, void* d_ws, size_t ws_size,
                              hipStream_t stream) {
  const float* x   = (const float*)d_in[0];
  const float* Wxh = (const float*)d_in[1];
  const float* Whh = (const float*)d_in[2];
  const float* bh  = (const float*)d_in[3];
  float* out = (float*)d_out;

  const size_t wh_bytes = (size_t)DIM * HID * sizeof(half_t);   // 128 KB
  const size_t need = wh_bytes + 4096;                          // + flags

  if (ws_size >= need) {
    half_t* Wh = (half_t*)d_ws;
    unsigned int* flags = (unsigned int*)((char*)d_ws + wh_bytes);
    prep_kernel<<<dim3((DIM * HID) / 1024), dim3(256), 0, stream>>>(Wxh, Wh, flags);
    fused_kernel<<<dim3(64 + BATCH * NSEG), dim3(512), 0, stream>>>(
        x, Wh, Whh, bh, out, flags, SEQT);
  } else {
    xproj_kernel<<<dim3((BATCH * SEQT) / 64), dim3(256), 0, stream>>>(x, Wxh, bh, out);
    rnn_kernel<<<dim3(BATCH), dim3(512), 0, stream>>>(Whh, out, SEQT);
  }
}